// Round 7
// baseline (570.891 us; speedup 1.0000x reference)
//
#include <hip/hip_runtime.h>

// HubnormTripletLoss, N=8192.
// P = Sinkhorn(exp(-(1-s)/lamb), 5 iters) == P0 * R[i] * C[j]  (diagonal scaling).
// Dense fp8-e4m3 Q (64MB), cache-resident after pass0 (sims NT-read once).
// R6 post-mortem: fused row+col kernel regressed via 4x part traffic (16MB vs
// 4MB per iter). R7: eliminate part/colred ENTIRELY:
//   - k_colmv atomicAdds 64-row partials into Csum[j] (128 adds/col, fire-and-
//     forget) and zeroes the other Csum buffer for iteration k+1 (kernel-
//     boundary-ordered double buffer; pass0 zeroes buf0).
//   - k_rowstep / k_loss compute C_j = 1/Csum[j] on the fly (~2us chip-wide);
//     k_loss computes dvec = qdiag*R/Csum inline (no dvec kernel).
// 11 dispatches, 10 Q-passes (structural minimum), no intermediate buffers.
//   pass0: quantize sims->Q, R1=1/rowsum(quantized), qdiag, zero Csum0, out=0
//   iter k (x5): k_colmv (8x128 blk): Csum[k&1] += Q^T R; zero Csum[(k+1)&1]
//                k_rowstep (2048 blk, k<4): R = 1/(Q . (1/Csum[k&1]))
//   k_loss (8x64): hinge over all pairs, C and dvec inline, skip i==j

#define NN 8192u
#define MARGIN 0.2f
#define KF (1.4426950408889634f / 0.012f)  // log2(e)/lamb

typedef float f32x4 __attribute__((ext_vector_type(4)));

__device__ __forceinline__ float wave_sum(float v) {
#pragma unroll
  for (int off = 32; off; off >>= 1) v += __shfl_down(v, off, 64);
  return v;
}

// ============================ FAST DENSE-FP8 PATH ============================

// ---- pass0: quantize -> dense Q, R = 1/rowsum(quantized), qdiag, zeros ------
__global__ __launch_bounds__(256) void k_pass0(const float* __restrict__ sims,
                                               uint* __restrict__ Qd,
                                               float* __restrict__ R,
                                               float* __restrict__ qdiag,
                                               float* __restrict__ Csum0,
                                               float* __restrict__ out) {
  __shared__ float red[4];
  const uint row = blockIdx.x, t = threadIdx.x;
  const uint lane = t & 63u, wid = t >> 6;
  if (row == 0u && t == 0u) *out = 0.f;      // d_out poisoned 0xAA each call
  if (row < 32u) Csum0[row * 256u + t] = 0.f;  // zero iteration-0 accumulator
  float acc = 0.f;
#pragma unroll
  for (uint ch = 0; ch < 8u; ++ch) {
    const uint col0 = ch * 1024u + t * 4u;
    // nontemporal: sims read exactly once; keep Q resident in caches instead
    const f32x4 s = __builtin_nontemporal_load(
        (const f32x4*)(sims + (size_t)row * NN + col0));
    int p = 0;
    p = __builtin_amdgcn_cvt_pk_fp8_f32(exp2f((s[0] - 1.f) * KF),
                                        exp2f((s[1] - 1.f) * KF), p, false);
    p = __builtin_amdgcn_cvt_pk_fp8_f32(exp2f((s[2] - 1.f) * KF),
                                        exp2f((s[3] - 1.f) * KF), p, true);
    const uint up = (uint)p;
    Qd[((size_t)row * NN + col0) >> 2] = up;
    auto lo = __builtin_amdgcn_cvt_pk_f32_fp8(p, false);
    auto hi = __builtin_amdgcn_cvt_pk_f32_fp8(p, true);
    acc += (lo[0] + lo[1]) + (hi[0] + hi[1]);  // sum QUANTIZED values
    if (row - col0 < 4u)  // this thread's quad holds the diagonal
      qdiag[row] = __builtin_amdgcn_cvt_f32_fp8(
          (int)((up >> ((row - col0) * 8u)) & 0xFFu), 0);
  }
  const float wacc = wave_sum(acc);
  if (lane == 0u) red[wid] = wacc;
  __syncthreads();
  if (t == 0u) R[row] = 1.f / (red[0] + red[1] + red[2] + red[3]);
}

// ---- col matvec: Csum[j] += sum_{64 rows} Q[i,j]*R[i]; zero next buffer -----
// grid (8, 128) x 256 thr — R1-proven streaming shape, partials via atomics.
__global__ __launch_bounds__(256) void k_colmv(const uint* __restrict__ Qd,
                                               const float* __restrict__ R,
                                               float* __restrict__ Csum,
                                               float* __restrict__ CsumNext) {
  const uint t = threadIdx.x;
  const uint col = blockIdx.x * 1024u + t * 4u;
  const uint row0 = blockIdx.y * 64u;
  // zero next iteration's accumulator: 8 floats per block, 1024 blocks = 8192
  if (t < 8u) CsumNext[(blockIdx.y * 8u + blockIdx.x) * 8u + t] = 0.f;
  float a0 = 0.f, a1 = 0.f, a2 = 0.f, a3 = 0.f;
#pragma unroll 8
  for (uint rr = 0; rr < 64u; ++rr) {
    const uint row = row0 + rr;
    const float Rr = R[row];  // block-uniform -> scalar load
    const uint q = Qd[((size_t)row * NN + col) >> 2];
    auto lo = __builtin_amdgcn_cvt_pk_f32_fp8((int)q, false);
    auto hi = __builtin_amdgcn_cvt_pk_f32_fp8((int)q, true);
    a0 += lo[0] * Rr; a1 += lo[1] * Rr; a2 += hi[0] * Rr; a3 += hi[1] * Rr;
  }
  atomicAdd(&Csum[col + 0u], a0);
  atomicAdd(&Csum[col + 1u], a1);
  atomicAdd(&Csum[col + 2u], a2);
  atomicAdd(&Csum[col + 3u], a3);
}

// ---- row step: R[i] = 1/sum_j Q[i,j]*(1/Csum[j]), 4 rows/block --------------
__global__ __launch_bounds__(256) void k_rowstep(const uint* __restrict__ Qd,
                                                 const float* __restrict__ Csum,
                                                 float* __restrict__ R) {
  __shared__ float red[4][4];
  const uint t = threadIdx.x;
  const uint row0 = blockIdx.x * 4u;
  float a0 = 0.f, a1 = 0.f, a2 = 0.f, a3 = 0.f;
#pragma unroll
  for (uint it = 0; it < 8u; ++it) {
    const uint col = it * 1024u + t * 4u;
    const float4 s = *(const float4*)(Csum + col);
    float4 c;
    c.x = 1.f / s.x; c.y = 1.f / s.y; c.z = 1.f / s.z; c.w = 1.f / s.w;
    const uint base = (row0 * 2048u) + (col >> 2);  // dwords; 2048 dwords/row
    uint q = Qd[base];
    auto lo = __builtin_amdgcn_cvt_pk_f32_fp8((int)q, false);
    auto hi = __builtin_amdgcn_cvt_pk_f32_fp8((int)q, true);
    a0 += lo[0] * c.x + lo[1] * c.y + hi[0] * c.z + hi[1] * c.w;
    q = Qd[base + 2048u];
    lo = __builtin_amdgcn_cvt_pk_f32_fp8((int)q, false);
    hi = __builtin_amdgcn_cvt_pk_f32_fp8((int)q, true);
    a1 += lo[0] * c.x + lo[1] * c.y + hi[0] * c.z + hi[1] * c.w;
    q = Qd[base + 4096u];
    lo = __builtin_amdgcn_cvt_pk_f32_fp8((int)q, false);
    hi = __builtin_amdgcn_cvt_pk_f32_fp8((int)q, true);
    a2 += lo[0] * c.x + lo[1] * c.y + hi[0] * c.z + hi[1] * c.w;
    q = Qd[base + 6144u];
    lo = __builtin_amdgcn_cvt_pk_f32_fp8((int)q, false);
    hi = __builtin_amdgcn_cvt_pk_f32_fp8((int)q, true);
    a3 += lo[0] * c.x + lo[1] * c.y + hi[0] * c.z + hi[1] * c.w;
  }
#pragma unroll
  for (int off = 32; off; off >>= 1) {
    a0 += __shfl_down(a0, off, 64);
    a1 += __shfl_down(a1, off, 64);
    a2 += __shfl_down(a2, off, 64);
    a3 += __shfl_down(a3, off, 64);
  }
  const uint lane = t & 63u, wid = t >> 6;
  if (lane == 0u) {
    red[wid][0] = a0; red[wid][1] = a1; red[wid][2] = a2; red[wid][3] = a3;
  }
  __syncthreads();
  if (t < 4u)
    R[row0 + t] = 1.f / (red[0][t] + red[1][t] + red[2][t] + red[3][t]);
}

// ---- loss: sum_{i!=j} max(P-d[j]+m,0)+max(P-d[i]+m,0); C, dvec inline -------
__global__ __launch_bounds__(256) void k_loss(const uint* __restrict__ Qd,
                                              const float* __restrict__ R,
                                              const float* __restrict__ Csum,
                                              const float* __restrict__ qdiag,
                                              float* __restrict__ out) {
  __shared__ float red[4];
  const uint t = threadIdx.x;
  const uint col = blockIdx.x * 1024u + t * 4u;
  const uint row0 = blockIdx.y * 128u;
  const float4 cs = *(const float4*)(Csum + col);
  float4 c4;
  c4.x = 1.f / cs.x; c4.y = 1.f / cs.y; c4.z = 1.f / cs.z; c4.w = 1.f / cs.w;
  const float4 r4 = *(const float4*)(R + col);
  const float4 qd4 = *(const float4*)(qdiag + col);
  float4 d4;  // dvec for this col quad: qdiag * R * C
  d4.x = qd4.x * r4.x * c4.x;
  d4.y = qd4.y * r4.y * c4.y;
  d4.z = qd4.z * r4.z * c4.z;
  d4.w = qd4.w * r4.w * c4.w;
  float acc = 0.f;
#pragma unroll 4
  for (uint rr = 0; rr < 128u; ++rr) {
    const uint row = row0 + rr;
    const float Rr = R[row];                            // uniform -> scalar
    const float dr = qdiag[row] * Rr * (1.f / Csum[row]);  // dvec[row] inline
    const uint q = Qd[((size_t)row * NN + col) >> 2];
    auto lo = __builtin_amdgcn_cvt_pk_f32_fp8((int)q, false);
    auto hi = __builtin_amdgcn_cvt_pk_f32_fp8((int)q, true);
    float p, h;
    p = lo[0] * Rr * c4.x;
    h = fmaxf(p - d4.x + MARGIN, 0.f) + fmaxf(p - dr + MARGIN, 0.f);
    acc += (row == col + 0u) ? 0.f : h;
    p = lo[1] * Rr * c4.y;
    h = fmaxf(p - d4.y + MARGIN, 0.f) + fmaxf(p - dr + MARGIN, 0.f);
    acc += (row == col + 1u) ? 0.f : h;
    p = hi[0] * Rr * c4.z;
    h = fmaxf(p - d4.z + MARGIN, 0.f) + fmaxf(p - dr + MARGIN, 0.f);
    acc += (row == col + 2u) ? 0.f : h;
    p = hi[1] * Rr * c4.w;
    h = fmaxf(p - d4.w + MARGIN, 0.f) + fmaxf(p - dr + MARGIN, 0.f);
    acc += (row == col + 3u) ? 0.f : h;
  }
  const float v = wave_sum(acc);
  const uint lane = t & 63u, wid = t >> 6;
  if (lane == 0u) red[wid] = v;
  __syncthreads();
  if (t == 0u) atomicAdd(out, red[0] + red[1] + red[2] + red[3]);
}

static void run_fast(const float* sims, float* out, void* ws,
                     hipStream_t stream) {
  uint* Qd = (uint*)ws;                           // 64 MB dense fp8
  float* R = (float*)(Qd + (size_t)NN * NN / 4u);
  float* qd = R + NN;
  float* Csum0 = qd + NN;
  float* Csum1 = Csum0 + NN;

  k_pass0<<<8192, 256, 0, stream>>>(sims, Qd, R, qd, Csum0, out);
  for (int it = 0; it < 5; ++it) {
    float* A = (it & 1) ? Csum1 : Csum0;
    float* B = (it & 1) ? Csum0 : Csum1;
    k_colmv<<<dim3(8, 128), 256, 0, stream>>>(Qd, R, A, B);
    if (it < 4) k_rowstep<<<2048, 256, 0, stream>>>(Qd, A, R);
  }
  k_loss<<<dim3(8, 64), 256, 0, stream>>>(Qd, R, Csum0, qd, out);
}

// =============== FALLBACK: dense recompute-from-sims path ====================

__global__ __launch_bounds__(256) void k_pass0d(const float* __restrict__ sims,
                                                float* __restrict__ R) {
  __shared__ float red[4];
  const uint row = blockIdx.x;
  const uint t = threadIdx.x;
  float acc = 0.f;
#pragma unroll
  for (uint ch = 0; ch < 8; ++ch) {
    const uint col = ch * 1024u + t * 4u;
    const float4 s = *(const float4*)(sims + (size_t)row * NN + col);
    acc += exp2f((s.x - 1.f) * KF) + exp2f((s.y - 1.f) * KF) +
           exp2f((s.z - 1.f) * KF) + exp2f((s.w - 1.f) * KF);
  }
  float v = wave_sum(acc);
  const int lane = threadIdx.x & 63, wid = threadIdx.x >> 6;
  if (lane == 0) red[wid] = v;
  __syncthreads();
  if (t == 0) R[row] = 1.f / (red[0] + red[1] + red[2] + red[3]);
}

__global__ __launch_bounds__(256) void k_colmvd(const float* __restrict__ sims,
                                                const float* __restrict__ R,
                                                float* __restrict__ part) {
  const uint t = threadIdx.x;
  const uint col = blockIdx.x * 1024u + t * 4u;
  const uint row0 = blockIdx.y * 64u;
  float a0 = 0.f, a1 = 0.f, a2 = 0.f, a3 = 0.f;
#pragma unroll 8
  for (uint rr = 0; rr < 64u; ++rr) {
    const uint row = row0 + rr;
    const float Rr = R[row];
    const float4 s = *(const float4*)(sims + (size_t)row * NN + col);
    a0 += exp2f((s.x - 1.f) * KF) * Rr;
    a1 += exp2f((s.y - 1.f) * KF) * Rr;
    a2 += exp2f((s.z - 1.f) * KF) * Rr;
    a3 += exp2f((s.w - 1.f) * KF) * Rr;
  }
  float4 o; o.x = a0; o.y = a1; o.z = a2; o.w = a3;
  *(float4*)(part + (size_t)blockIdx.y * NN + col) = o;
}

__global__ __launch_bounds__(1024) void k_colredd(
    const float* __restrict__ part, float* __restrict__ Cg, int fin,
    const float* __restrict__ sims, const float* __restrict__ R,
    float* __restrict__ dvec, float* __restrict__ out) {
  __shared__ float red2[3][256];
  const uint t = threadIdx.x;
  const uint lj = t & 255u;
  const uint q = t >> 8;
  const uint j = blockIdx.x * 256u + lj;
  float s = 0.f;
  const uint r0 = q * 32u;
#pragma unroll 8
  for (uint r = r0; r < r0 + 32u; ++r) s += part[(size_t)r * NN + j];
  if (q) red2[q - 1][lj] = s;
  __syncthreads();
  if (q == 0) {
    s += red2[0][lj] + red2[1][lj] + red2[2][lj];
    const float c = 1.f / s;
    Cg[j] = c;
    if (fin) {
      dvec[j] = exp2f((sims[(size_t)j * 8193u] - 1.f) * KF) * R[j] * c;
      if (j == 0) *out = 0.f;
    }
  }
}

__global__ __launch_bounds__(256) void k_rowmvd(const float* __restrict__ sims,
                                                const float* __restrict__ Cg,
                                                float* __restrict__ R) {
  __shared__ float red[4][4];
  const uint t = threadIdx.x;
  const uint row0 = blockIdx.x * 4u;
  float a0 = 0.f, a1 = 0.f, a2 = 0.f, a3 = 0.f;
#pragma unroll
  for (uint it = 0; it < 8u; ++it) {
    const uint col = it * 1024u + t * 4u;
    const float4 c = *(const float4*)(Cg + col);
    const float* sp = sims + (size_t)row0 * NN + col;
    const float4 s0 = *(const float4*)(sp);
    const float4 s1 = *(const float4*)(sp + NN);
    const float4 s2 = *(const float4*)(sp + 2u * NN);
    const float4 s3 = *(const float4*)(sp + 3u * NN);
    a0 += exp2f((s0.x - 1.f) * KF) * c.x + exp2f((s0.y - 1.f) * KF) * c.y +
          exp2f((s0.z - 1.f) * KF) * c.z + exp2f((s0.w - 1.f) * KF) * c.w;
    a1 += exp2f((s1.x - 1.f) * KF) * c.x + exp2f((s1.y - 1.f) * KF) * c.y +
          exp2f((s1.z - 1.f) * KF) * c.z + exp2f((s1.w - 1.f) * KF) * c.w;
    a2 += exp2f((s2.x - 1.f) * KF) * c.x + exp2f((s2.y - 1.f) * KF) * c.y +
          exp2f((s2.z - 1.f) * KF) * c.z + exp2f((s2.w - 1.f) * KF) * c.w;
    a3 += exp2f((s3.x - 1.f) * KF) * c.x + exp2f((s3.y - 1.f) * KF) * c.y +
          exp2f((s3.z - 1.f) * KF) * c.z + exp2f((s3.w - 1.f) * KF) * c.w;
  }
#pragma unroll
  for (int off = 32; off; off >>= 1) {
    a0 += __shfl_down(a0, off, 64);
    a1 += __shfl_down(a1, off, 64);
    a2 += __shfl_down(a2, off, 64);
    a3 += __shfl_down(a3, off, 64);
  }
  const uint lane = t & 63u, wid = t >> 6;
  if (lane == 0) {
    red[wid][0] = a0; red[wid][1] = a1; red[wid][2] = a2; red[wid][3] = a3;
  }
  __syncthreads();
  if (t < 4u)
    R[row0 + t] = 1.f / (red[0][t] + red[1][t] + red[2][t] + red[3][t]);
}

__global__ __launch_bounds__(256) void k_lossd(const float* __restrict__ sims,
                                               const float* __restrict__ R,
                                               const float* __restrict__ Cg,
                                               const float* __restrict__ dvec,
                                               float* __restrict__ out) {
  __shared__ float red[4];
  const uint t = threadIdx.x;
  const uint col = blockIdx.x * 1024u + t * 4u;
  const uint row0 = blockIdx.y * 128u;
  const float4 c4 = *(const float4*)(Cg + col);
  const float4 d4 = *(const float4*)(dvec + col);
  float acc = 0.f;
#pragma unroll 4
  for (uint rr = 0; rr < 128u; ++rr) {
    const uint row = row0 + rr;
    const float Rr = R[row];
    const float dr = dvec[row];
    const float4 s = *(const float4*)(sims + (size_t)row * NN + col);
    const float f0 = exp2f((s.x - 1.f) * KF);
    const float f1 = exp2f((s.y - 1.f) * KF);
    const float f2 = exp2f((s.z - 1.f) * KF);
    const float f3 = exp2f((s.w - 1.f) * KF);
    float p, h;
    p = f0 * Rr * c4.x;
    h = fmaxf(p - d4.x + MARGIN, 0.f) + fmaxf(p - dr + MARGIN, 0.f);
    acc += (row == col + 0u) ? 0.f : h;
    p = f1 * Rr * c4.y;
    h = fmaxf(p - d4.y + MARGIN, 0.f) + fmaxf(p - dr + MARGIN, 0.f);
    acc += (row == col + 1u) ? 0.f : h;
    p = f2 * Rr * c4.z;
    h = fmaxf(p - d4.z + MARGIN, 0.f) + fmaxf(p - dr + MARGIN, 0.f);
    acc += (row == col + 2u) ? 0.f : h;
    p = f3 * Rr * c4.w;
    h = fmaxf(p - d4.w + MARGIN, 0.f) + fmaxf(p - dr + MARGIN, 0.f);
    acc += (row == col + 3u) ? 0.f : h;
  }
  float v = wave_sum(acc);
  const int lane = threadIdx.x & 63, wid = threadIdx.x >> 6;
  if (lane == 0) red[wid] = v;
  __syncthreads();
  if (t == 0) atomicAdd(out, red[0] + red[1] + red[2] + red[3]);
}

static void run_dense(const float* sims, float* out, void* ws,
                      hipStream_t stream) {
  float* R = (float*)ws;
  float* C = R + NN;
  float* dv = C + NN;
  float* part = dv + NN;  // [128][NN]
  k_pass0d<<<8192, 256, 0, stream>>>(sims, R);
  for (int it = 0; it < 5; ++it) {
    k_colmvd<<<dim3(8, 128), 256, 0, stream>>>(sims, R, part);
    k_colredd<<<32, 1024, 0, stream>>>(part, C, (it == 4) ? 1 : 0, sims, R, dv,
                                       out);
    if (it < 4) k_rowmvd<<<2048, 256, 0, stream>>>(sims, C, R);
  }
  k_lossd<<<dim3(8, 64), 256, 0, stream>>>(sims, R, C, dv, out);
}

// ================================ dispatch ===================================

extern "C" void kernel_launch(void* const* d_in, const int* in_sizes, int n_in,
                              void* d_out, int out_size, void* d_ws,
                              size_t ws_size, hipStream_t stream) {
  const float* sims = (const float*)d_in[0];
  float* out = (float*)d_out;
  // fast: Qd 64MB + R + qdiag + Csum0 + Csum1
  const size_t need_fast = (size_t)NN * NN + 4u * (size_t)NN * sizeof(float);
  if (ws_size >= need_fast) {
    run_fast(sims, out, d_ws, stream);
  } else {
    run_dense(sims, out, d_ws, stream);  // recompute from sims (slow, safe)
  }
}